// Round 15
// baseline (93.616 us; speedup 1.0000x reference)
//
#include <hip/hip_runtime.h>
#include <math.h>

#define N_MEL 80
#define B_    64
#define T_    2000
#define L_    200
#define ROWS   (B_*N_MEL)        // 5120
#define NTOT   (B_*N_MEL*T_)     // 10,240,000
#define GATE_N (B_*T_)           // 128,000
#define ATT_ROWS (B_*T_)         // 128,000
#define AV_ROWS 64
#define NVIOL  (ATT_ROWS/AV_ROWS)  // 2000

// ws layout (float indices). ALL writes are non-atomic per-block partials;
// nothing requires pre-zeroed memory (no memset, no atomics anywhere).
#define WS_ROWPART 0                         // 5120*8
#define WS_M8      (WS_ROWPART + ROWS*8)     // 8*64*6400
#define WS_GATEP   (WS_M8 + 8*64*6400)       // 64
#define WS_VIOLP   (WS_GATEP + 64)           // 2000
#define WS_GFP     (WS_VIOLP + NVIOL)        // 64

typedef __attribute__((ext_vector_type(8)))  short bf16x8;
typedef __attribute__((ext_vector_type(16))) float f32x16;
typedef unsigned short ush;

__device__ __forceinline__ float blockReduceSum256(float v) {
    __shared__ float red[4];
    #pragma unroll
    for (int off = 32; off; off >>= 1) v += __shfl_down(v, off, 64);
    int lane = threadIdx.x & 63, w = threadIdx.x >> 6;
    if (lane == 0) red[w] = v;
    __syncthreads();
    if (threadIdx.x == 0) v = red[0] + red[1] + red[2] + red[3];
    return v;  // valid on thread 0 only
}

__device__ __forceinline__ unsigned short f2bf(float f) {
    unsigned u = __float_as_uint(f);
    u = (u + 0x7fffu + ((u >> 16) & 1u)) >> 16;   // RNE
    return (unsigned short)u;
}

__device__ __forceinline__ void merge4(float& b, int& p) {
    #pragma unroll
    for (int m = 1; m <= 2; m <<= 1) {
        float ob = __shfl_xor(b, m, 64);
        int   op = __shfl_xor(p, m, 64);
        if (ob > b || (ob == b && op < p)) { b = ob; p = op; }
    }
}

// argmax: loads 0..11 unconditional, load 12 predicated; register-array MLP.
// First-index tie-break preserved. FAST ONLY in its own kernel (needs its own
// register budget — fused versions serialized the loads, R9-R12 evidence).
__device__ __forceinline__ void scan_sub(const float* __restrict__ rowp, int q,
                                         float& bOut, int& pOut) {
    const float4* rp = (const float4*)rowp;
    float4 v[13];
    #pragma unroll
    for (int i = 0; i < 12; i++) v[i] = rp[q + 4*i];
    v[12] = make_float4(-1.f, -1.f, -1.f, -1.f);   // att in [0,1): never wins
    if (q < 2) v[12] = rp[q + 48];
    float bx=-1.f, by=-1.f, bz=-1.f, bw=-1.f;
    int jx=0, jy=0, jz=0, jw=0;
    #pragma unroll
    for (int i = 0; i < 13; i++) {
        int j = q + 4*i;
        if (v[i].x > bx) { bx = v[i].x; jx = j; }
        if (v[i].y > by) { by = v[i].y; jy = j; }
        if (v[i].z > bz) { bz = v[i].z; jz = j; }
        if (v[i].w > bw) { bw = v[i].w; jw = j; }
    }
    float b = bx; int p = 4*jx;
    if (by > b || (by == b && 4*jy+1 < p)) { b = by; p = 4*jy+1; }
    if (bz > b || (bz == b && 4*jz+2 < p)) { b = bz; p = 4*jz+2; }
    if (bw > b || (bw == b && 4*jw+3 < p)) { b = bw; p = 4*jw+3; }
    bOut = b; pOut = p;
}

// ========== K1: melrow — R7 block-per-row form (measured ~21 us) ==========
__global__ __launch_bounds__(256) void k_melrow(const float* __restrict__ mo,
                                                const float* __restrict__ mp,
                                                const float* __restrict__ mt,
                                                float* __restrict__ rowpart) {
    const int row = blockIdx.x;            // b*80 + c
    const long base = (long)row * T_;
    const float4* mo4 = (const float4*)(mo + base);
    const float4* mp4 = (const float4*)(mp + base);
    const float4* mt4 = (const float4*)(mt + base);

    float s1 = 0, s2 = 0, sl1 = 0, std_ = 0, sp = 0, sp2 = 0, st = 0, st2 = 0;
    for (int i = threadIdx.x; i < T_/4; i += 256) {
        float4 a = mo4[i], p = mp4[i], t = mt4[i];
        float e0 = a.x - t.x, e1 = a.y - t.y, e2 = a.z - t.z, e3 = a.w - t.w;
        s1 += e0*e0 + e1*e1 + e2*e2 + e3*e3;
        float d0 = p.x - t.x, d1 = p.y - t.y, d2 = p.z - t.z, d3 = p.w - t.w;
        s2 += d0*d0 + d1*d1 + d2*d2 + d3*d3;
        sl1 += fabsf(d0) + fabsf(d1) + fabsf(d2) + fabsf(d3);
        sp  += p.x + p.y + p.z + p.w;
        sp2 += p.x*p.x + p.y*p.y + p.z*p.z + p.w*p.w;
        st  += t.x + t.y + t.z + t.w;
        st2 += t.x*t.x + t.y*t.y + t.z*t.z + t.w*t.w;
        float q1 = d1 - d0, q2 = d2 - d1, q3 = d3 - d2;
        std_ += q1*q1 + q2*q2 + q3*q3;
        if (i > 0) {
            float dprev = mp[base + 4*i - 1] - mt[base + 4*i - 1];
            float q0 = d0 - dprev;
            std_ += q0*q0;
        }
    }

    __shared__ float red[4][8];
    float vals[8] = {s1, s2, sl1, std_, sp, sp2, st, st2};
    #pragma unroll
    for (int k = 0; k < 8; k++) {
        float v = vals[k];
        #pragma unroll
        for (int off = 32; off; off >>= 1) v += __shfl_down(v, off, 64);
        vals[k] = v;
    }
    int lane = threadIdx.x & 63, w = threadIdx.x >> 6;
    if (lane == 0) {
        #pragma unroll
        for (int k = 0; k < 8; k++) red[w][k] = vals[k];
    }
    __syncthreads();
    if (threadIdx.x == 0) {
        #pragma unroll
        for (int k = 0; k < 8; k++)
            rowpart[row*8 + k] = red[0][k] + red[1][k] + red[2][k] + red[3][k];
    }
}

// ========== K2: Gram partial M8[kc][b] = D * S^T via bf16 MFMA ==========
// Runs right after melrow: mel inputs L3-hot. 192 threads = 3 waves;
// LDS [96][24] double-buffered; non-atomic stores.
__global__ __launch_bounds__(192) void k_gram(const float* __restrict__ mp,
                                              const float* __restrict__ mt,
                                              float* __restrict__ M8) {
    const int b  = blockIdx.x >> 3;
    const int kc = blockIdx.x & 7;
    const int k0 = kc * 256;
    const int NS = (kc < 7) ? 16 : 13;     // 16-K steps ({7x256, 208})

    __shared__ ush Dls[2][96][24];
    __shared__ ush Sls[2][96][24];

    const int tid  = threadIdx.x;
    const int row  = tid >> 1;             // 0..95
    const int half = tid & 1;
    const int lane = tid & 63;
    const int wv   = tid >> 6;
    const long bbase = (long)b * (N_MEL * T_);
    const float* prow = mp + bbase + (long)row * T_ + k0 + half * 8;
    const float* trow = mt + bbase + (long)row * T_ + k0 + half * 8;
    const bool rv = (row < N_MEL);

    f32x16 acc0 = {}, acc1 = {}, acc2 = {};
    float4 pa0, pa1, ta0, ta1;

    auto loadreg = [&](int s) {
        if (rv) {
            pa0 = *(const float4*)(prow + s*16);
            pa1 = *(const float4*)(prow + s*16 + 4);
            ta0 = *(const float4*)(trow + s*16);
            ta1 = *(const float4*)(trow + s*16 + 4);
        } else {
            pa0 = pa1 = ta0 = ta1 = make_float4(0.f, 0.f, 0.f, 0.f);
        }
    };
    auto writelds = [&](int buf) {
        bf16x8 d, s;
        d[0]=f2bf(pa0.x-ta0.x); d[1]=f2bf(pa0.y-ta0.y); d[2]=f2bf(pa0.z-ta0.z); d[3]=f2bf(pa0.w-ta0.w);
        d[4]=f2bf(pa1.x-ta1.x); d[5]=f2bf(pa1.y-ta1.y); d[6]=f2bf(pa1.z-ta1.z); d[7]=f2bf(pa1.w-ta1.w);
        s[0]=f2bf(pa0.x+ta0.x); s[1]=f2bf(pa0.y+ta0.y); s[2]=f2bf(pa0.z+ta0.z); s[3]=f2bf(pa0.w+ta0.w);
        s[4]=f2bf(pa1.x+ta1.x); s[5]=f2bf(pa1.y+ta1.y); s[6]=f2bf(pa1.z+ta1.z); s[7]=f2bf(pa1.w+ta1.w);
        *(bf16x8*)&Dls[buf][row][half*8] = d;
        *(bf16x8*)&Sls[buf][row][half*8] = s;
    };

    loadreg(0);
    writelds(0);
    __syncthreads();

    const int frow = lane & 31;
    const int fkh  = lane >> 5;
    for (int s = 0; s < NS; s++) {
        const int cur = s & 1;
        if (s + 1 < NS) loadreg(s + 1);
        bf16x8 af = *(const bf16x8*)&Dls[cur][wv*32 + frow][fkh*8];
        bf16x8 b0 = *(const bf16x8*)&Sls[cur][      frow][fkh*8];
        bf16x8 b1 = *(const bf16x8*)&Sls[cur][ 32 + frow][fkh*8];
        bf16x8 b2 = *(const bf16x8*)&Sls[cur][ 64 + frow][fkh*8];
        acc0 = __builtin_amdgcn_mfma_f32_32x32x16_bf16(af, b0, acc0, 0, 0, 0);
        acc1 = __builtin_amdgcn_mfma_f32_32x32x16_bf16(af, b1, acc1, 0, 0, 0);
        acc2 = __builtin_amdgcn_mfma_f32_32x32x16_bf16(af, b2, acc2, 0, 0, 0);
        if (s + 1 < NS) writelds((s + 1) & 1);
        __syncthreads();
    }

    // C/D layout (verified m74/m101): col=lane&31, row=(r&3)+8*(r>>2)+4*(lane>>5)
    float* Mb = M8 + ((long)(kc * B_ + b)) * 6400;
    #pragma unroll
    for (int r = 0; r < 16; r++) {
        int row32 = (r & 3) + 8 * (r >> 2) + 4 * (lane >> 5);
        int c = wv * 32 + row32;
        if (c < N_MEL) {
            Mb[c*80 + frow]      = acc0[r];
            Mb[c*80 + 32 + frow] = acc1[r];
            if (frow < 16) Mb[c*80 + 64 + frow] = acc2[r];
        }
    }
}

// ========== K3: gram finalize ==========
__global__ __launch_bounds__(256) void k_gramfin(const float* __restrict__ ws_ro,
                                                 float* __restrict__ gfp) {
    __shared__ float Ms[N_MEL][N_MEL + 1];
    const float* M8 = ws_ro + WS_M8;
    const int b = blockIdx.x;
    const float inv = 1.0f / (float)(N_MEL * T_);

    for (int i = threadIdx.x; i < 6400; i += 256) {
        float m = 0.f;
        #pragma unroll
        for (int kc = 0; kc < 8; kc++)
            m += M8[((long)(kc * B_ + b)) * 6400 + i];
        Ms[i / N_MEL][i % N_MEL] = m;
    }
    __syncthreads();

    float s = 0.f;
    for (int i = threadIdx.x; i < 6400; i += 256) {
        int c = i / N_MEL, d = i % N_MEL;
        float g = 0.5f * (Ms[c][d] + Ms[d][c]) * inv;
        s += g * g;
    }
    float tot = blockReduceSum256(s);
    if (threadIdx.x == 0) gfp[b] = tot;
}

// ========== K4: argviol + gate (standalone — own register budget) ==========
__global__ __launch_bounds__(256, 2) void k_argviol(const float* __restrict__ att,
                                                    const float* __restrict__ gx,
                                                    const float* __restrict__ gt,
                                                    float* __restrict__ ws) {
    float* violp = ws + WS_VIOLP;
    float* gatep = ws + WS_GATEP;

    if (blockIdx.x >= NVIOL) {
        // ---------------- gate: BCE-with-logits partials ----------------
        const int gb = blockIdx.x - NVIOL;   // 0..63
        const float4* x4 = (const float4*)gx;
        const float4* t4 = (const float4*)gt;
        float s = 0;
        for (int i = gb*256 + threadIdx.x; i < GATE_N/4; i += 64*256) {
            float4 x = x4[i], t = t4[i];
            float xs[4] = {x.x, x.y, x.z, x.w}, ts[4] = {t.x, t.y, t.z, t.w};
            #pragma unroll
            for (int k = 0; k < 4; k++)
                s += fmaxf(xs[k], 0.0f) - xs[k]*ts[k] + log1pf(expf(-fabsf(xs[k])));
        }
        float tot = blockReduceSum256(s);
        if (threadIdx.x == 0) gatep[gb] = tot;
        return;
    }

    __shared__ float pk[AV_ROWS + 1];
    const int ab = blockIdx.x;
    const int g = threadIdx.x >> 2;
    const int q = threadIdx.x & 3;
    const int r0 = ab * AV_ROWS;
    const int r  = r0 + g;

    float b; int p;
    scan_sub(att + (long)r * L_, q, b, p);
    merge4(b, p);
    if (q == 0) pk[g] = (float)p;

    const int rb = r0 + AV_ROWS;
    const bool need_b = ((rb % T_) != 0) && (rb < ATT_ROWS);
    if (g == 0 && need_b) {
        float b2; int p2;
        scan_sub(att + (long)rb * L_, q, b2, p2);
        merge4(b2, p2);
        if (q == 0) pk[AV_ROWS] = (float)p2;
    }
    __syncthreads();

    float s = 0;
    if (threadIdx.x < AV_ROWS) {
        int rr = r0 + threadIdx.x;
        if (((rr + 1) % T_) != 0)
            s = fmaxf(pk[threadIdx.x] - pk[threadIdx.x + 1], 0.0f);
    }
    float tot = blockReduceSum256(s);
    if (threadIdx.x == 0) violp[ab] = tot;
}

// ========== K5: melred + partial sums + final combine ==========
__global__ __launch_bounds__(256) void k_final2(const float* __restrict__ ws_ro,
                                                float* __restrict__ out) {
    const float* rowpart = ws_ro + WS_ROWPART;
    const float* gatep   = ws_ro + WS_GATEP;
    const float* violp   = ws_ro + WS_VIOLP;
    const float* gfp     = ws_ro + WS_GFP;

    float a[11] = {0,0,0,0,0,0,0,0,0,0,0};
    for (int row = threadIdx.x; row < ROWS; row += 256) {
        const float4 lo = *(const float4*)(rowpart + row*8);
        const float4 hi = *(const float4*)(rowpart + row*8 + 4);
        int c = row % N_MEL;
        float wc = (c >= 3*N_MEL/4) ? 0.8f : ((c >= N_MEL/4) ? 1.5f : 1.0f);
        float fw = expf(-(float)c / 20.0f);
        a[0] += lo.x;                 // sum(mo-mt)^2
        a[1] += lo.y;                 // sum(mp-mt)^2
        a[2] += wc*wc*lo.y;           // weighted mse
        a[3] += lo.z;                 // |d|
        a[4] += lo.w;                 // tdiff^2
        a[5] += fw*lo.y;              // perceptual weighted
        float md = (hi.x - hi.z) * (1.0f / T_);
        a[6] += md*md;
        float vp = (hi.y - hi.x*hi.x*(1.0f/T_)) * (1.0f/(T_-1));
        float vt = (hi.w - hi.z*hi.z*(1.0f/T_)) * (1.0f/(T_-1));
        float vd = vp - vt;
        a[7] += vd*vd;
    }
    for (int i = threadIdx.x; i < NVIOL; i += 256) a[9] += violp[i];
    if (threadIdx.x < 64) { a[8] = gatep[threadIdx.x]; a[10] = gfp[threadIdx.x]; }

    __shared__ float red[4][11];
    #pragma unroll
    for (int k = 0; k < 11; k++) {
        float v = a[k];
        #pragma unroll
        for (int off = 32; off; off >>= 1) v += __shfl_down(v, off, 64);
        a[k] = v;
    }
    int lane = threadIdx.x & 63, w = threadIdx.x >> 6;
    if (lane == 0) {
        #pragma unroll
        for (int k = 0; k < 11; k++) red[w][k] = a[k];
    }
    __syncthreads();
    if (threadIdx.x == 0) {
        float r[11];
        #pragma unroll
        for (int k = 0; k < 11; k++) r[k] = red[0][k] + red[1][k] + red[2][k] + red[3][k];
        const float invN = 1.0f / (float)NTOT;
        float mel        = (r[0] + r[1]) * invN;
        float gate       = 1.3f * r[8] / (float)GATE_N;
        float wmse       = r[2] * invN;
        float l1         = r[3] * invN;
        float sdiff      = r[4] / (float)(B_ * N_MEL * (T_ - 1));
        float spectral   = wmse + 0.3f*l1 + 0.2f*sdiff;
        float perceptual = r[5]*invN + 0.5f*l1;
        float mean_loss  = r[6] / (float)ROWS;
        float var_loss   = r[7] / (float)ROWS;
        float gram       = r[10] / (float)(B_ * 6400);
        float style      = mean_loss + var_loss + 0.5f*gram;
        float mono       = r[9] / (float)(B_ * T_);
        out[0] = mel + gate + 0.3f*spectral + 0.2f*perceptual + 0.1f*style + 0.1f*mono;
    }
}

extern "C" void kernel_launch(void* const* d_in, const int* in_sizes, int n_in,
                              void* d_out, int out_size, void* d_ws, size_t ws_size,
                              hipStream_t stream) {
    const float* mo  = (const float*)d_in[0];
    const float* mp  = (const float*)d_in[1];
    const float* mt  = (const float*)d_in[2];
    const float* gx  = (const float*)d_in[3];
    const float* gt  = (const float*)d_in[4];
    const float* att = (const float*)d_in[5];
    float* ws = (float*)d_ws;

    k_melrow <<<ROWS,       256, 0, stream>>>(mo, mp, mt, ws + WS_ROWPART);
    k_gram   <<<512,        192, 0, stream>>>(mp, mt, ws + WS_M8);
    k_gramfin<<<64,         256, 0, stream>>>(ws, ws + WS_GFP);
    k_argviol<<<NVIOL + 64, 256, 0, stream>>>(att, gx, gt, ws);
    k_final2 <<<1,          256, 0, stream>>>(ws, (float*)d_out);
}

// Round 16
// 89.027 us; speedup vs baseline: 1.0515x; 1.0515x over previous
//
#include <hip/hip_runtime.h>
#include <math.h>

#define N_MEL 80
#define B_    64
#define T_    2000
#define L_    200
#define ROWS   (B_*N_MEL)        // 5120
#define NTOT   (B_*N_MEL*T_)     // 10,240,000
#define GATE_N (B_*T_)           // 128,000
#define ATT_ROWS (B_*T_)         // 128,000
#define AV_ROWS 64
#define NVIOL  (ATT_ROWS/AV_ROWS)  // 2000

// K1 mega-kernel block ranges
#define G_MELROW 5120
#define G_GRAM   512
#define G_ARGV   NVIOL
#define G_GATE   64

// ws layout (float indices). ALL writes are non-atomic per-block partials;
// nothing requires pre-zeroed memory (no memset, no atomics anywhere).
#define WS_ROWPART 0                        // 5120*8
#define WS_M8      (WS_ROWPART + ROWS*8)    // 8*64*6400
#define WS_GATEP   (WS_M8 + 8*64*6400)      // 64
#define WS_VIOLP   (WS_GATEP + 64)          // 2000
#define WS_GFP     (WS_VIOLP + NVIOL)       // 64

typedef __attribute__((ext_vector_type(8)))  short bf16x8;
typedef __attribute__((ext_vector_type(16))) float f32x16;
typedef unsigned short ush;

__device__ __forceinline__ float blockReduceSum256(float v) {
    __shared__ float red[4];
    #pragma unroll
    for (int off = 32; off; off >>= 1) v += __shfl_down(v, off, 64);
    int lane = threadIdx.x & 63, w = threadIdx.x >> 6;
    if (lane == 0) red[w] = v;
    __syncthreads();
    if (threadIdx.x == 0) v = red[0] + red[1] + red[2] + red[3];
    return v;  // valid on thread 0 only
}

__device__ __forceinline__ unsigned short f2bf(float f) {
    unsigned u = __float_as_uint(f);
    u = (u + 0x7fffu + ((u >> 16) & 1u)) >> 16;   // RNE
    return (unsigned short)u;
}

// argmax helpers: 4 threads/row, interleaved float4 split, first-index ties.
__device__ __forceinline__ void scan_sub(const float* __restrict__ rowp, int q,
                                         float& bOut, int& pOut) {
    const float4* rp = (const float4*)rowp;
    float bx=-1.f, by=-1.f, bz=-1.f, bw=-1.f;   // att is uniform[0,1): -1 < all
    int jx=0, jy=0, jz=0, jw=0;
    const int n = (q < 2) ? 13 : 12;            // j = q + 4i <= 49
    #pragma unroll
    for (int i = 0; i < 13; i++) {
        if (i < n) {
            int j = q + 4*i;
            float4 v = rp[j];
            if (v.x > bx) { bx = v.x; jx = j; }
            if (v.y > by) { by = v.y; jy = j; }
            if (v.z > bz) { bz = v.z; jz = j; }
            if (v.w > bw) { bw = v.w; jw = j; }
        }
    }
    float b = bx; int p = 4*jx;
    if (by > b || (by == b && 4*jy+1 < p)) { b = by; p = 4*jy+1; }
    if (bz > b || (bz == b && 4*jz+2 < p)) { b = bz; p = 4*jz+2; }
    if (bw > b || (bw == b && 4*jw+3 < p)) { b = bw; p = 4*jw+3; }
    bOut = b; pOut = p;
}

__device__ __forceinline__ void merge4(float& b, int& p) {
    #pragma unroll
    for (int m = 1; m <= 2; m <<= 1) {
        float ob = __shfl_xor(b, m, 64);
        int   op = __shfl_xor(p, m, 64);
        if (ob > b || (ob == b && op < p)) { b = ob; p = op; }
    }
}

// =================== K1: mega-kernel (all independent producers) ===================
__global__ __launch_bounds__(256) void k_mega(const float* __restrict__ mo,
                                              const float* __restrict__ mp,
                                              const float* __restrict__ mt,
                                              const float* __restrict__ gx,
                                              const float* __restrict__ gt,
                                              const float* __restrict__ att,
                                              float* __restrict__ ws) {
    __shared__ alignas(16) unsigned char smem[18432];
    const int bid = blockIdx.x;
    float* rowpart = ws + WS_ROWPART;
    float* M8      = ws + WS_M8;
    float* gatep   = ws + WS_GATEP;
    float* violp   = ws + WS_VIOLP;

    if (bid < G_MELROW) {
        // ---------------- melrow: per-(b,c) row pass over mel tensors ----------------
        const int row = bid;               // b*80 + c
        const long base = (long)row * T_;
        const float4* mo4 = (const float4*)(mo + base);
        const float4* mp4 = (const float4*)(mp + base);
        const float4* mt4 = (const float4*)(mt + base);

        float s1 = 0, s2 = 0, sl1 = 0, std_ = 0, sp = 0, sp2 = 0, st = 0, st2 = 0;
        for (int i = threadIdx.x; i < T_/4; i += 256) {
            float4 a = mo4[i], p = mp4[i], t = mt4[i];
            float e0 = a.x - t.x, e1 = a.y - t.y, e2 = a.z - t.z, e3 = a.w - t.w;
            s1 += e0*e0 + e1*e1 + e2*e2 + e3*e3;
            float d0 = p.x - t.x, d1 = p.y - t.y, d2 = p.z - t.z, d3 = p.w - t.w;
            s2 += d0*d0 + d1*d1 + d2*d2 + d3*d3;
            sl1 += fabsf(d0) + fabsf(d1) + fabsf(d2) + fabsf(d3);
            sp  += p.x + p.y + p.z + p.w;
            sp2 += p.x*p.x + p.y*p.y + p.z*p.z + p.w*p.w;
            st  += t.x + t.y + t.z + t.w;
            st2 += t.x*t.x + t.y*t.y + t.z*t.z + t.w*t.w;
            float q1 = d1 - d0, q2 = d2 - d1, q3 = d3 - d2;
            std_ += q1*q1 + q2*q2 + q3*q3;
            if (i > 0) {
                float dprev = mp[base + 4*i - 1] - mt[base + 4*i - 1];
                float q0 = d0 - dprev;
                std_ += q0*q0;
            }
        }

        float (*red)[8] = reinterpret_cast<float(*)[8]>(smem);
        float vals[8] = {s1, s2, sl1, std_, sp, sp2, st, st2};
        #pragma unroll
        for (int k = 0; k < 8; k++) {
            float v = vals[k];
            #pragma unroll
            for (int off = 32; off; off >>= 1) v += __shfl_down(v, off, 64);
            vals[k] = v;
        }
        int lane = threadIdx.x & 63, w = threadIdx.x >> 6;
        if (lane == 0) {
            #pragma unroll
            for (int k = 0; k < 8; k++) red[w][k] = vals[k];
        }
        __syncthreads();
        if (threadIdx.x == 0) {
            #pragma unroll
            for (int k = 0; k < 8; k++)
                rowpart[row*8 + k] = red[0][k] + red[1][k] + red[2][k] + red[3][k];
        }
        return;
    }

    if (bid < G_MELROW + G_GRAM) {
        // ---------------- gram: M8[kc][b] = D * S^T via bf16 MFMA ----------------
        const int gb = bid - G_MELROW;
        const int b  = gb >> 3;
        const int kc = gb & 7;
        const int k0 = kc * 256;
        const int NS = (kc < 7) ? 16 : 13;   // 16-K steps ({7x256, 208})

        ush (*Dls)[96][24] = reinterpret_cast<ush(*)[96][24]>(smem);
        ush (*Sls)[96][24] = reinterpret_cast<ush(*)[96][24]>(smem + 9216);

        const int tid  = threadIdx.x;
        const bool act = (tid < 192);        // 3 staging/compute waves; wave 3 syncs only
        const int row  = tid >> 1;           // 0..95 (for act)
        const int half = tid & 1;
        const int lane = tid & 63;
        const int wv   = tid >> 6;
        const long bbase = (long)b * (N_MEL * T_);
        const float* prow = mp + bbase + (long)(row < 80 ? row : 0) * T_ + k0 + half * 8;
        const float* trow = mt + bbase + (long)(row < 80 ? row : 0) * T_ + k0 + half * 8;
        const bool rv = act && (row < N_MEL);

        f32x16 acc0 = {}, acc1 = {}, acc2 = {};
        float4 pa0, pa1, ta0, ta1;

        auto loadreg = [&](int s) {
            if (rv) {
                pa0 = *(const float4*)(prow + s*16);
                pa1 = *(const float4*)(prow + s*16 + 4);
                ta0 = *(const float4*)(trow + s*16);
                ta1 = *(const float4*)(trow + s*16 + 4);
            } else {
                pa0 = pa1 = ta0 = ta1 = make_float4(0.f, 0.f, 0.f, 0.f);
            }
        };
        auto writelds = [&](int buf) {
            bf16x8 d, s;
            d[0]=f2bf(pa0.x-ta0.x); d[1]=f2bf(pa0.y-ta0.y); d[2]=f2bf(pa0.z-ta0.z); d[3]=f2bf(pa0.w-ta0.w);
            d[4]=f2bf(pa1.x-ta1.x); d[5]=f2bf(pa1.y-ta1.y); d[6]=f2bf(pa1.z-ta1.z); d[7]=f2bf(pa1.w-ta1.w);
            s[0]=f2bf(pa0.x+ta0.x); s[1]=f2bf(pa0.y+ta0.y); s[2]=f2bf(pa0.z+ta0.z); s[3]=f2bf(pa0.w+ta0.w);
            s[4]=f2bf(pa1.x+ta1.x); s[5]=f2bf(pa1.y+ta1.y); s[6]=f2bf(pa1.z+ta1.z); s[7]=f2bf(pa1.w+ta1.w);
            *(bf16x8*)&Dls[buf][row][half*8] = d;
            *(bf16x8*)&Sls[buf][row][half*8] = s;
        };

        if (act) { loadreg(0); writelds(0); }
        __syncthreads();

        const int frow = lane & 31;
        const int fkh  = lane >> 5;
        for (int s = 0; s < NS; s++) {
            const int cur = s & 1;
            if (act) {
                if (s + 1 < NS) loadreg(s + 1);
                bf16x8 af = *(const bf16x8*)&Dls[cur][wv*32 + frow][fkh*8];
                bf16x8 b0 = *(const bf16x8*)&Sls[cur][      frow][fkh*8];
                bf16x8 b1 = *(const bf16x8*)&Sls[cur][ 32 + frow][fkh*8];
                bf16x8 b2 = *(const bf16x8*)&Sls[cur][ 64 + frow][fkh*8];
                acc0 = __builtin_amdgcn_mfma_f32_32x32x16_bf16(af, b0, acc0, 0, 0, 0);
                acc1 = __builtin_amdgcn_mfma_f32_32x32x16_bf16(af, b1, acc1, 0, 0, 0);
                acc2 = __builtin_amdgcn_mfma_f32_32x32x16_bf16(af, b2, acc2, 0, 0, 0);
                if (s + 1 < NS) writelds((s + 1) & 1);
            }
            __syncthreads();
        }

        // C/D layout (verified m74/m101): col=lane&31, row=(r&3)+8*(r>>2)+4*(lane>>5)
        if (act) {
            float* Mb = M8 + ((long)(kc * B_ + b)) * 6400;
            #pragma unroll
            for (int r = 0; r < 16; r++) {
                int row32 = (r & 3) + 8 * (r >> 2) + 4 * (lane >> 5);
                int c = wv * 32 + row32;
                if (c < N_MEL) {
                    Mb[c*80 + frow]      = acc0[r];
                    Mb[c*80 + 32 + frow] = acc1[r];
                    if (frow < 16) Mb[c*80 + 64 + frow] = acc2[r];
                }
            }
        }
        return;
    }

    if (bid < G_MELROW + G_GRAM + G_ARGV) {
        // ---------------- argviol: fused argmax + monotonic violation ----------------
        const int ab = bid - (G_MELROW + G_GRAM);
        float* pk = reinterpret_cast<float*>(smem);     // AV_ROWS+1 floats
        const int g = threadIdx.x >> 2;
        const int q = threadIdx.x & 3;
        const int r0 = ab * AV_ROWS;
        const int r  = r0 + g;

        float b; int p;
        scan_sub(att + (long)r * L_, q, b, p);
        merge4(b, p);
        if (q == 0) pk[g] = (float)p;

        const int rb = r0 + AV_ROWS;
        const bool need_b = ((rb % T_) != 0) && (rb < ATT_ROWS);
        if (g == 0 && need_b) {
            float b2; int p2;
            scan_sub(att + (long)rb * L_, q, b2, p2);
            merge4(b2, p2);
            if (q == 0) pk[AV_ROWS] = (float)p2;
        }
        __syncthreads();

        float s = 0;
        if (threadIdx.x < AV_ROWS) {
            int rr = r0 + threadIdx.x;
            if (((rr + 1) % T_) != 0)
                s = fmaxf(pk[threadIdx.x] - pk[threadIdx.x + 1], 0.0f);
        }
        float tot = blockReduceSum256(s);
        if (threadIdx.x == 0) violp[ab] = tot;
        return;
    }

    // ---------------- gate: BCE-with-logits partials ----------------
    {
        const int gb = bid - (G_MELROW + G_GRAM + G_ARGV);   // 0..63
        const float4* x4 = (const float4*)gx;
        const float4* t4 = (const float4*)gt;
        float s = 0;
        for (int i = gb*256 + threadIdx.x; i < GATE_N/4; i += G_GATE*256) {
            float4 x = x4[i], t = t4[i];
            float xs[4] = {x.x, x.y, x.z, x.w}, ts[4] = {t.x, t.y, t.z, t.w};
            #pragma unroll
            for (int k = 0; k < 4; k++)
                s += fmaxf(xs[k], 0.0f) - xs[k]*ts[k] + log1pf(expf(-fabsf(xs[k])));
        }
        float tot = blockReduceSum256(s);
        if (threadIdx.x == 0) gatep[gb] = tot;
    }
}

// =================== K2: gram finalize ===================
// One block per batch. Stage kc-summed 80x80 M in LDS (coalesced reads of 8
// contiguous planes), symmetrize+square. Pad 81: transpose stride 17 mod 32.
__global__ __launch_bounds__(256) void k_gramfin(const float* __restrict__ ws_ro,
                                                 float* __restrict__ gfp) {
    __shared__ float Ms[N_MEL][N_MEL + 1];
    const float* M8 = ws_ro + WS_M8;
    const int b = blockIdx.x;
    const float inv = 1.0f / (float)(N_MEL * T_);

    for (int i = threadIdx.x; i < 6400; i += 256) {
        float m = 0.f;
        #pragma unroll
        for (int kc = 0; kc < 8; kc++)
            m += M8[((long)(kc * B_ + b)) * 6400 + i];
        Ms[i / N_MEL][i % N_MEL] = m;
    }
    __syncthreads();

    float s = 0.f;
    for (int i = threadIdx.x; i < 6400; i += 256) {
        int c = i / N_MEL, d = i % N_MEL;
        float g = 0.5f * (Ms[c][d] + Ms[d][c]) * inv;
        s += g * g;
    }
    float tot = blockReduceSum256(s);
    if (threadIdx.x == 0) gfp[b] = tot;
}

// =================== K3: melred + partial sums + final combine ===================
__global__ __launch_bounds__(256) void k_final2(const float* __restrict__ ws_ro,
                                                float* __restrict__ out) {
    const float* rowpart = ws_ro + WS_ROWPART;
    const float* gatep   = ws_ro + WS_GATEP;
    const float* violp   = ws_ro + WS_VIOLP;
    const float* gfp     = ws_ro + WS_GFP;

    float a[11] = {0,0,0,0,0,0,0,0,0,0,0};
    for (int row = threadIdx.x; row < ROWS; row += 256) {
        const float4 lo = *(const float4*)(rowpart + row*8);
        const float4 hi = *(const float4*)(rowpart + row*8 + 4);
        int c = row % N_MEL;
        float wc = (c >= 3*N_MEL/4) ? 0.8f : ((c >= N_MEL/4) ? 1.5f : 1.0f);
        float fw = expf(-(float)c / 20.0f);
        a[0] += lo.x;                 // sum(mo-mt)^2
        a[1] += lo.y;                 // sum(mp-mt)^2
        a[2] += wc*wc*lo.y;           // weighted mse
        a[3] += lo.z;                 // |d|
        a[4] += lo.w;                 // tdiff^2
        a[5] += fw*lo.y;              // perceptual weighted
        float md = (hi.x - hi.z) * (1.0f / T_);
        a[6] += md*md;
        float vp = (hi.y - hi.x*hi.x*(1.0f/T_)) * (1.0f/(T_-1));
        float vt = (hi.w - hi.z*hi.z*(1.0f/T_)) * (1.0f/(T_-1));
        float vd = vp - vt;
        a[7] += vd*vd;
    }
    for (int i = threadIdx.x; i < NVIOL; i += 256) a[9] += violp[i];
    if (threadIdx.x < 64) { a[8] = gatep[threadIdx.x]; a[10] = gfp[threadIdx.x]; }

    __shared__ float red[4][11];
    #pragma unroll
    for (int k = 0; k < 11; k++) {
        float v = a[k];
        #pragma unroll
        for (int off = 32; off; off >>= 1) v += __shfl_down(v, off, 64);
        a[k] = v;
    }
    int lane = threadIdx.x & 63, w = threadIdx.x >> 6;
    if (lane == 0) {
        #pragma unroll
        for (int k = 0; k < 11; k++) red[w][k] = a[k];
    }
    __syncthreads();
    if (threadIdx.x == 0) {
        float r[11];
        #pragma unroll
        for (int k = 0; k < 11; k++) r[k] = red[0][k] + red[1][k] + red[2][k] + red[3][k];
        const float invN = 1.0f / (float)NTOT;
        float mel        = (r[0] + r[1]) * invN;
        float gate       = 1.3f * r[8] / (float)GATE_N;
        float wmse       = r[2] * invN;
        float l1         = r[3] * invN;
        float sdiff      = r[4] / (float)(B_ * N_MEL * (T_ - 1));
        float spectral   = wmse + 0.3f*l1 + 0.2f*sdiff;
        float perceptual = r[5]*invN + 0.5f*l1;
        float mean_loss  = r[6] / (float)ROWS;
        float var_loss   = r[7] / (float)ROWS;
        float gram       = r[10] / (float)(B_ * 6400);
        float style      = mean_loss + var_loss + 0.5f*gram;
        float mono       = r[9] / (float)(B_ * T_);
        out[0] = mel + gate + 0.3f*spectral + 0.2f*perceptual + 0.1f*style + 0.1f*mono;
    }
}

extern "C" void kernel_launch(void* const* d_in, const int* in_sizes, int n_in,
                              void* d_out, int out_size, void* d_ws, size_t ws_size,
                              hipStream_t stream) {
    const float* mo  = (const float*)d_in[0];
    const float* mp  = (const float*)d_in[1];
    const float* mt  = (const float*)d_in[2];
    const float* gx  = (const float*)d_in[3];
    const float* gt  = (const float*)d_in[4];
    const float* att = (const float*)d_in[5];
    float* ws = (float*)d_ws;

    const int g1 = G_MELROW + G_GRAM + G_ARGV + G_GATE;   // 7696
    k_mega   <<<g1, 256, 0, stream>>>(mo, mp, mt, gx, gt, att, ws);
    k_gramfin<<<64, 256, 0, stream>>>(ws, ws + WS_GFP);
    k_final2 <<<1,  256, 0, stream>>>(ws, (float*)d_out);
}